// Round 1
// baseline (394.042 us; speedup 1.0000x reference)
//
#include <hip/hip_runtime.h>
#include <hip/hip_bf16.h>

#define NPIX 1801
#define NT   256
#define NB   1024

// Analytic lookup-table inverse: pixel index of axial (q, r) is
// col_base(q) + r, for the reference's ordering (q major from -24..24,
// r minor from max(-24,-24-q)..min(24,24-q)).
__device__ __forceinline__ int col_base(int q) {
    int a = q + 24;
    return (q <= 0) ? (a * 26 + ((a * (a - 1)) >> 1))
                    : (900 + 49 * q - ((q * (q - 1)) >> 1));
}

__device__ __forceinline__ bool in_hex(int q, int r) {
    return (unsigned)(q + 24) <= 48u && (unsigned)(r + 24) <= 48u &&
           (unsigned)(q + r + 24) <= 48u;
}

__global__ __launch_bounds__(NT) void hexsplat_kernel(
    const float* __restrict__ xs, const float* __restrict__ ys,
    const float* __restrict__ vs, float* __restrict__ out, int n4)
{
    __shared__ float hist[NPIX];
    for (int i = threadIdx.x; i < NPIX; i += NT) hist[i] = 0.0f;
    __syncthreads();

    // neighbor stencil, reference order: (-1,0),(-1,1),(0,-1),(0,0),(0,1),(1,-1),(1,0)
    const float nox[7] = {-1.7320508075688772f, -0.8660254037844386f,
                          -0.8660254037844386f, 0.0f, 0.8660254037844386f,
                          0.8660254037844386f, 1.7320508075688772f};
    const float noy[7] = {0.0f, 1.5f, -1.5f, 0.0f, 1.5f, -1.5f, 0.0f};
    // per-neighbor (column select 0/1/2 relative to qb-1, r offset)
    const int ncol[7] = {0, 0, 1, 1, 1, 2, 2};
    const int nrow[7] = {0, 1, -1, 0, 1, -1, 0};
    const int nq_[7]  = {-1, -1, 0, 0, 0, 1, 1};

    const int tid = blockIdx.x * NT + threadIdx.x;
    const int stride = NB * NT;
    const float4* x4 = (const float4*)xs;
    const float4* y4 = (const float4*)ys;
    const float4* v4 = (const float4*)vs;

    for (int i = tid; i < n4; i += stride) {
        float4 xq = x4[i];
        float4 yq = y4[i];
        float4 vq = v4[i];
        #pragma unroll
        for (int k = 0; k < 4; ++k) {
            float px = (&xq.x)[k];
            float py = (&yq.x)[k];
            float pv = (&vq.x)[k];

            // cartesian -> fractional axial (hex_size == 1, rot == 0, offset == 0)
            float q = 0.5773502691896258f * px - 0.3333333333333333f * py;
            float r = 0.6666666666666666f * py;

            // axial (cube) round, matching jnp.round (half-to-even via rintf)
            float sn = -q - r;
            float qi = rintf(q), ri = rintf(r), si = rintf(sn);
            float dq = fabsf(qi - q), dr = fabsf(ri - r), ds = fabsf(si - sn);
            if (dq > dr && dq > ds)      qi = -ri - si;
            else if (dr > dq && dr > ds) ri = -qi - si;

            int qb = (int)qi;
            int rb = (int)ri;

            float dx = px - 1.7320508075688772f * (qi + 0.5f * ri);
            float dy = py - 1.5f * ri;

            // 7 neighbor Gaussian hex-distance weights (sum over ALL 7)
            float w[7];
            float wsum = 0.0f;
            #pragma unroll
            for (int nn = 0; nn < 7; ++nn) {
                float dxn = dx - nox[nn];
                float dyn = dy - noy[nn];
                float ady = fabsf(dyn);
                float hd = fmaxf(ady, 0.8660254037844386f * fabsf(dxn) + 0.5f * ady)
                           * 1.1547005383792517f;   // / inradius
                float t = hd + hd;                  // hd / 0.5
                float wi = __expf(-0.5f * t * t);
                w[nn] = wi;
                wsum += wi;
            }
            float vinv = pv / wsum;

            int b0 = col_base(qb - 1);
            int b1 = col_base(qb);
            int b2 = col_base(qb + 1);
            int cb[3] = {b0 + rb, b1 + rb, b2 + rb};

            // fast path: whole stencil strictly interior (always true for this input)
            bool interior = (unsigned)(qb + 23) <= 46u && (unsigned)(rb + 23) <= 46u &&
                            (unsigned)(qb + rb + 23) <= 46u;
            if (interior) {
                #pragma unroll
                for (int nn = 0; nn < 7; ++nn) {
                    atomicAdd(&hist[cb[ncol[nn]] + nrow[nn]], w[nn] * vinv);
                }
            } else {
                #pragma unroll
                for (int nn = 0; nn < 7; ++nn) {
                    int qn = qb + nq_[nn];
                    int rn = rb + nrow[nn];
                    if (in_hex(qn, rn)) {
                        atomicAdd(&hist[cb[ncol[nn]] + nrow[nn]], w[nn] * vinv);
                    }
                }
            }
        }
    }

    __syncthreads();
    for (int i = threadIdx.x; i < NPIX; i += NT) {
        atomicAdd(&out[i], hist[i]);
    }
}

extern "C" void kernel_launch(void* const* d_in, const int* in_sizes, int n_in,
                              void* d_out, int out_size, void* d_ws, size_t ws_size,
                              hipStream_t stream) {
    const float* x = (const float*)d_in[0];
    const float* y = (const float*)d_in[1];
    const float* v = (const float*)d_in[2];
    float* out = (float*)d_out;
    int n = in_sizes[0];
    int n4 = n / 4;

    hipMemsetAsync(out, 0, (size_t)out_size * sizeof(float), stream);
    hexsplat_kernel<<<NB, NT, 0, stream>>>(x, y, v, out, n4);
}

// Round 2
// 393.930 us; speedup vs baseline: 1.0003x; 1.0003x over previous
//
#include <hip/hip_runtime.h>
#include <hip/hip_bf16.h>

#define NPIX 1801
#define NT   256
#define NB   2048

// Analytic lookup-table inverse: pixel index of axial (q, r) is
// col_base(q) + r, for the reference's ordering (q major from -24..24,
// r minor from max(-24,-24-q)..min(24,24-q)).
__device__ __forceinline__ int col_base(int q) {
    int a = q + 24;
    return (q <= 0) ? (a * 26 + ((a * (a - 1)) >> 1))
                    : (900 + 49 * q - ((q * (q - 1)) >> 1));
}

__device__ __forceinline__ bool in_hex(int q, int r) {
    return (unsigned)(q + 24) <= 48u && (unsigned)(r + 24) <= 48u &&
           (unsigned)(q + r + 24) <= 48u;
}

// Hardware fp32 atomic add (ds_add_f32 / global_atomic_add_f32), bypassing
// the CAS-loop lowering used when -munsafe-fp-atomics is absent.
__device__ __forceinline__ void hw_atomic_add(float* p, float v) {
#if defined(__AMDGCN__) || defined(__HIP_DEVICE_COMPILE__)
    unsafeAtomicAdd(p, v);
#else
    atomicAdd(p, v);
#endif
}

__global__ __launch_bounds__(NT) void hexsplat_kernel(
    const float* __restrict__ xs, const float* __restrict__ ys,
    const float* __restrict__ vs, float* __restrict__ out, int n4)
{
    __shared__ float hist[NPIX];
    for (int i = threadIdx.x; i < NPIX; i += NT) hist[i] = 0.0f;
    __syncthreads();

    // neighbor stencil, reference order: (-1,0),(-1,1),(0,-1),(0,0),(0,1),(1,-1),(1,0)
    const float nox[7] = {-1.7320508075688772f, -0.8660254037844386f,
                          -0.8660254037844386f, 0.0f, 0.8660254037844386f,
                          0.8660254037844386f, 1.7320508075688772f};
    const float noy[7] = {0.0f, 1.5f, -1.5f, 0.0f, 1.5f, -1.5f, 0.0f};
    // per-neighbor (column select 0/1/2 relative to qb-1, r offset)
    const int ncol[7] = {0, 0, 1, 1, 1, 2, 2};
    const int nrow[7] = {0, 1, -1, 0, 1, -1, 0};
    const int nq_[7]  = {-1, -1, 0, 0, 0, 1, 1};

    const int tid = blockIdx.x * NT + threadIdx.x;
    const int stride = NB * NT;
    const float4* x4 = (const float4*)xs;
    const float4* y4 = (const float4*)ys;
    const float4* v4 = (const float4*)vs;

    for (int i = tid; i < n4; i += stride) {
        float4 xq = x4[i];
        float4 yq = y4[i];
        float4 vq = v4[i];
        #pragma unroll
        for (int k = 0; k < 4; ++k) {
            float px = (&xq.x)[k];
            float py = (&yq.x)[k];
            float pv = (&vq.x)[k];

            // cartesian -> fractional axial (hex_size == 1, rot == 0, offset == 0)
            float q = 0.5773502691896258f * px - 0.3333333333333333f * py;
            float r = 0.6666666666666666f * py;

            // axial (cube) round, matching jnp.round (half-to-even via rintf)
            float sn = -q - r;
            float qi = rintf(q), ri = rintf(r), si = rintf(sn);
            float dq = fabsf(qi - q), dr = fabsf(ri - r), ds = fabsf(si - sn);
            if (dq > dr && dq > ds)      qi = -ri - si;
            else if (dr > dq && dr > ds) ri = -qi - si;

            int qb = (int)qi;
            int rb = (int)ri;

            float dx = px - 1.7320508075688772f * (qi + 0.5f * ri);
            float dy = py - 1.5f * ri;

            // 7 neighbor Gaussian hex-distance weights (sum over ALL 7)
            float w[7];
            float wsum = 0.0f;
            #pragma unroll
            for (int nn = 0; nn < 7; ++nn) {
                float dxn = dx - nox[nn];
                float dyn = dy - noy[nn];
                float ady = fabsf(dyn);
                float hd = fmaxf(ady, 0.8660254037844386f * fabsf(dxn) + 0.5f * ady)
                           * 1.1547005383792517f;   // / inradius
                float t = hd + hd;                  // hd / 0.5
                float wi = __expf(-0.5f * t * t);
                w[nn] = wi;
                wsum += wi;
            }
            float vinv = pv / wsum;

            int b0 = col_base(qb - 1);
            int b1 = col_base(qb);
            int b2 = col_base(qb + 1);
            int cb[3] = {b0 + rb, b1 + rb, b2 + rb};

            // fast path: whole stencil strictly interior (always true for this input)
            bool interior = (unsigned)(qb + 23) <= 46u && (unsigned)(rb + 23) <= 46u &&
                            (unsigned)(qb + rb + 23) <= 46u;
            if (interior) {
                #pragma unroll
                for (int nn = 0; nn < 7; ++nn) {
                    hw_atomic_add(&hist[cb[ncol[nn]] + nrow[nn]], w[nn] * vinv);
                }
            } else {
                #pragma unroll
                for (int nn = 0; nn < 7; ++nn) {
                    int qn = qb + nq_[nn];
                    int rn = rb + nrow[nn];
                    if (in_hex(qn, rn)) {
                        hw_atomic_add(&hist[cb[ncol[nn]] + nrow[nn]], w[nn] * vinv);
                    }
                }
            }
        }
    }

    __syncthreads();
    for (int i = threadIdx.x; i < NPIX; i += NT) {
        hw_atomic_add(&out[i], hist[i]);
    }
}

extern "C" void kernel_launch(void* const* d_in, const int* in_sizes, int n_in,
                              void* d_out, int out_size, void* d_ws, size_t ws_size,
                              hipStream_t stream) {
    const float* x = (const float*)d_in[0];
    const float* y = (const float*)d_in[1];
    const float* v = (const float*)d_in[2];
    float* out = (float*)d_out;
    int n = in_sizes[0];
    int n4 = n / 4;

    hipMemsetAsync(out, 0, (size_t)out_size * sizeof(float), stream);
    hexsplat_kernel<<<NB, NT, 0, stream>>>(x, y, v, out, n4);
}

// Round 3
// 393.440 us; speedup vs baseline: 1.0015x; 1.0012x over previous
//
#include <hip/hip_runtime.h>
#include <hip/hip_bf16.h>

#define NPIX 1801
#define NT   256
#define NB   2048

// Analytic lookup-table inverse: pixel index of axial (q, r) is
// col_base(q) + r, for the reference's ordering (q major from -24..24,
// r minor from max(-24,-24-q)..min(24,24-q)).
__device__ __forceinline__ int col_base(int q) {
    int a = q + 24;
    return (q <= 0) ? (a * 26 + ((a * (a - 1)) >> 1))
                    : (900 + 49 * q - ((q * (q - 1)) >> 1));
}

__device__ __forceinline__ bool in_hex(int q, int r) {
    return (unsigned)(q + 24) <= 48u && (unsigned)(r + 24) <= 48u &&
           (unsigned)(q + r + 24) <= 48u;
}

// Fire-and-forget LDS fp32 atomic add: non-returning ds_add_f32.
// The wave does NOT wait for the result — only lgkmcnt drains at the barrier.
__device__ __forceinline__ void lds_add(float* p, float v) {
    auto lp = (__attribute__((address_space(3))) float*)p;
    asm volatile("ds_add_f32 %0, %1" : : "v"(lp), "v"(v) : "memory");
}

// Global fp32 hardware atomic (global_atomic_add_f32 on gfx90a+/gfx950).
__device__ __forceinline__ void hw_atomic_add(float* p, float v) {
    unsafeAtomicAdd(p, v);
}

__global__ __launch_bounds__(NT) void hexsplat_kernel(
    const float* __restrict__ xs, const float* __restrict__ ys,
    const float* __restrict__ vs, float* __restrict__ out, int n4)
{
    __shared__ float hist[NPIX];
    for (int i = threadIdx.x; i < NPIX; i += NT) hist[i] = 0.0f;
    __syncthreads();

    // neighbor stencil, reference order: (-1,0),(-1,1),(0,-1),(0,0),(0,1),(1,-1),(1,0)
    const float nox[7] = {-1.7320508075688772f, -0.8660254037844386f,
                          -0.8660254037844386f, 0.0f, 0.8660254037844386f,
                          0.8660254037844386f, 1.7320508075688772f};
    const float noy[7] = {0.0f, 1.5f, -1.5f, 0.0f, 1.5f, -1.5f, 0.0f};
    // per-neighbor (column select 0/1/2 relative to qb-1, r offset)
    const int ncol[7] = {0, 0, 1, 1, 1, 2, 2};
    const int nrow[7] = {0, 1, -1, 0, 1, -1, 0};
    const int nq_[7]  = {-1, -1, 0, 0, 0, 1, 1};

    const int tid = blockIdx.x * NT + threadIdx.x;
    const int stride = NB * NT;
    const float4* x4 = (const float4*)xs;
    const float4* y4 = (const float4*)ys;
    const float4* v4 = (const float4*)vs;

    for (int i = tid; i < n4; i += stride) {
        float4 xq = x4[i];
        float4 yq = y4[i];
        float4 vq = v4[i];
        #pragma unroll
        for (int k = 0; k < 4; ++k) {
            float px = (&xq.x)[k];
            float py = (&yq.x)[k];
            float pv = (&vq.x)[k];

            // cartesian -> fractional axial (hex_size == 1, rot == 0, offset == 0)
            float q = 0.5773502691896258f * px - 0.3333333333333333f * py;
            float r = 0.6666666666666666f * py;

            // axial (cube) round, matching jnp.round (half-to-even via rintf)
            float sn = -q - r;
            float qi = rintf(q), ri = rintf(r), si = rintf(sn);
            float dq = fabsf(qi - q), dr = fabsf(ri - r), ds = fabsf(si - sn);
            if (dq > dr && dq > ds)      qi = -ri - si;
            else if (dr > dq && dr > ds) ri = -qi - si;

            int qb = (int)qi;
            int rb = (int)ri;

            float dx = px - 1.7320508075688772f * (qi + 0.5f * ri);
            float dy = py - 1.5f * ri;

            // 7 neighbor Gaussian hex-distance weights (sum over ALL 7)
            float w[7];
            float wsum = 0.0f;
            #pragma unroll
            for (int nn = 0; nn < 7; ++nn) {
                float dxn = dx - nox[nn];
                float dyn = dy - noy[nn];
                float ady = fabsf(dyn);
                float hd = fmaxf(ady, 0.8660254037844386f * fabsf(dxn) + 0.5f * ady)
                           * 1.1547005383792517f;   // / inradius
                float t = hd + hd;                  // hd / 0.5
                float wi = __expf(-0.5f * t * t);
                w[nn] = wi;
                wsum += wi;
            }
            float vinv = pv / wsum;

            int b0 = col_base(qb - 1);
            int b1 = col_base(qb);
            int b2 = col_base(qb + 1);
            int cb[3] = {b0 + rb, b1 + rb, b2 + rb};

            // fast path: whole stencil strictly interior (always true for this input)
            bool interior = (unsigned)(qb + 23) <= 46u && (unsigned)(rb + 23) <= 46u &&
                            (unsigned)(qb + rb + 23) <= 46u;
            if (interior) {
                #pragma unroll
                for (int nn = 0; nn < 7; ++nn) {
                    lds_add(&hist[cb[ncol[nn]] + nrow[nn]], w[nn] * vinv);
                }
            } else {
                #pragma unroll
                for (int nn = 0; nn < 7; ++nn) {
                    int qn = qb + nq_[nn];
                    int rn = rb + nrow[nn];
                    if (in_hex(qn, rn)) {
                        lds_add(&hist[cb[ncol[nn]] + nrow[nn]], w[nn] * vinv);
                    }
                }
            }
        }
    }

    // drain our asm ds_add_f32 ops before reading hist back
    asm volatile("s_waitcnt lgkmcnt(0)" ::: "memory");
    __syncthreads();
    for (int i = threadIdx.x; i < NPIX; i += NT) {
        hw_atomic_add(&out[i], hist[i]);
    }
}

extern "C" void kernel_launch(void* const* d_in, const int* in_sizes, int n_in,
                              void* d_out, int out_size, void* d_ws, size_t ws_size,
                              hipStream_t stream) {
    const float* x = (const float*)d_in[0];
    const float* y = (const float*)d_in[1];
    const float* v = (const float*)d_in[2];
    float* out = (float*)d_out;
    int n = in_sizes[0];
    int n4 = n / 4;

    hipMemsetAsync(out, 0, (size_t)out_size * sizeof(float), stream);
    hexsplat_kernel<<<NB, NT, 0, stream>>>(x, y, v, out, n4);
}

// Round 4
// 153.135 us; speedup vs baseline: 2.5732x; 2.5692x over previous
//
#include <hip/hip_runtime.h>
#include <hip/hip_bf16.h>

#define NPIX 1801
#define NT   256
#define NB   2048

#define FXSCALE 1048576.0f          // 2^20
#define FXINV   (1.0f / 1048576.0f)

// Analytic lookup-table inverse: pixel index of axial (q, r) is
// col_base(q) + r, for the reference's ordering (q major from -24..24,
// r minor from max(-24,-24-q)..min(24,24-q)).
__device__ __forceinline__ int col_base(int q) {
    int a = q + 24;
    return (q <= 0) ? (a * 26 + ((a * (a - 1)) >> 1))
                    : (900 + 49 * q - ((q * (q - 1)) >> 1));
}

__device__ __forceinline__ bool in_hex(int q, int r) {
    return (unsigned)(q + 24) <= 48u && (unsigned)(r + 24) <= 48u &&
           (unsigned)(q + r + 24) <= 48u;
}

__global__ __launch_bounds__(NT) void hexsplat_kernel(
    const float* __restrict__ xs, const float* __restrict__ ys,
    const float* __restrict__ vs, unsigned int* __restrict__ acc, int n4)
{
    __shared__ unsigned int hist[NPIX];
    for (int i = threadIdx.x; i < NPIX; i += NT) hist[i] = 0u;
    __syncthreads();

    // neighbor stencil, reference order: (-1,0),(-1,1),(0,-1),(0,0),(0,1),(1,-1),(1,0)
    const float nox[7] = {-1.7320508075688772f, -0.8660254037844386f,
                          -0.8660254037844386f, 0.0f, 0.8660254037844386f,
                          0.8660254037844386f, 1.7320508075688772f};
    const float noy[7] = {0.0f, 1.5f, -1.5f, 0.0f, 1.5f, -1.5f, 0.0f};
    const int ncol[7] = {0, 0, 1, 1, 1, 2, 2};
    const int nrow[7] = {0, 1, -1, 0, 1, -1, 0};
    const int nq_[7]  = {-1, -1, 0, 0, 0, 1, 1};

    const int tid = blockIdx.x * NT + threadIdx.x;
    const int stride = NB * NT;
    const float4* x4 = (const float4*)xs;
    const float4* y4 = (const float4*)ys;
    const float4* v4 = (const float4*)vs;

    for (int i = tid; i < n4; i += stride) {
        float4 xq = x4[i];
        float4 yq = y4[i];
        float4 vq = v4[i];
        #pragma unroll
        for (int k = 0; k < 4; ++k) {
            float px = (&xq.x)[k];
            float py = (&yq.x)[k];
            float pv = (&vq.x)[k];

            // cartesian -> fractional axial (hex_size == 1, rot == 0, offset == 0)
            float q = 0.5773502691896258f * px - 0.3333333333333333f * py;
            float r = 0.6666666666666666f * py;

            // axial (cube) round, matching jnp.round (half-to-even via rintf)
            float sn = -q - r;
            float qi = rintf(q), ri = rintf(r), si = rintf(sn);
            float dq = fabsf(qi - q), dr = fabsf(ri - r), ds = fabsf(si - sn);
            if (dq > dr && dq > ds)      qi = -ri - si;
            else if (dr > dq && dr > ds) ri = -qi - si;

            int qb = (int)qi;
            int rb = (int)ri;

            float dx = px - 1.7320508075688772f * (qi + 0.5f * ri);
            float dy = py - 1.5f * ri;

            // 7 neighbor Gaussian hex-distance weights (sum over ALL 7)
            float w[7];
            float wsum = 0.0f;
            #pragma unroll
            for (int nn = 0; nn < 7; ++nn) {
                float dxn = dx - nox[nn];
                float dyn = dy - noy[nn];
                float ady = fabsf(dyn);
                float hd = fmaxf(ady, 0.8660254037844386f * fabsf(dxn) + 0.5f * ady)
                           * 1.1547005383792517f;   // / inradius
                float t = hd + hd;                  // hd / 0.5
                float wi = __expf(-0.5f * t * t);
                w[nn] = wi;
                wsum += wi;
            }
            // fixed-point contribution scale: exact mod-2^32 accumulation
            float vinv = (pv / wsum) * FXSCALE;

            int b0 = col_base(qb - 1);
            int b1 = col_base(qb);
            int b2 = col_base(qb + 1);
            int cb[3] = {b0 + rb, b1 + rb, b2 + rb};

            bool interior = (unsigned)(qb + 23) <= 46u && (unsigned)(rb + 23) <= 46u &&
                            (unsigned)(qb + rb + 23) <= 46u;
            if (interior) {
                #pragma unroll
                for (int nn = 0; nn < 7; ++nn) {
                    int c = __float2int_rn(w[nn] * vinv);
                    atomicAdd(&hist[cb[ncol[nn]] + nrow[nn]], (unsigned int)c);
                }
            } else {
                #pragma unroll
                for (int nn = 0; nn < 7; ++nn) {
                    int qn = qb + nq_[nn];
                    int rn = rb + nrow[nn];
                    if (in_hex(qn, rn)) {
                        int c = __float2int_rn(w[nn] * vinv);
                        atomicAdd(&hist[cb[ncol[nn]] + nrow[nn]], (unsigned int)c);
                    }
                }
            }
        }
    }

    __syncthreads();
    for (int i = threadIdx.x; i < NPIX; i += NT) {
        atomicAdd(&acc[i], hist[i]);   // exact mod-2^32 merge
    }
}

__global__ void finalize_kernel(const unsigned int* __restrict__ acc,
                                float* __restrict__ out)
{
    int i = blockIdx.x * blockDim.x + threadIdx.x;
    if (i < NPIX) out[i] = (float)(int)acc[i] * FXINV;
}

extern "C" void kernel_launch(void* const* d_in, const int* in_sizes, int n_in,
                              void* d_out, int out_size, void* d_ws, size_t ws_size,
                              hipStream_t stream) {
    const float* x = (const float*)d_in[0];
    const float* y = (const float*)d_in[1];
    const float* v = (const float*)d_in[2];
    float* out = (float*)d_out;
    unsigned int* acc = (unsigned int*)d_ws;
    int n = in_sizes[0];
    int n4 = n / 4;

    hipMemsetAsync(acc, 0, NPIX * sizeof(unsigned int), stream);
    hexsplat_kernel<<<NB, NT, 0, stream>>>(x, y, v, acc, n4);
    finalize_kernel<<<(NPIX + 255) / 256, 256, 0, stream>>>(acc, out);
}

// Round 5
// 137.158 us; speedup vs baseline: 2.8729x; 1.1165x over previous
//
#include <hip/hip_runtime.h>
#include <hip/hip_bf16.h>

#define NPIX 1801
#define NT   256
#define NB   4096
#define MAXSLICES 32

#define FXSCALE 1048576.0f          // 2^20
#define FXINV   (1.0f / 1048576.0f)
#define KHD 1.9614249f              // sqrt(2*log2(e)) / inradius ; w = exp2(-(KHD*u)^2)
#define KHX 1.6986438f              // 0.8660254 * KHD

#if __has_builtin(__builtin_amdgcn_exp2f)
#define EXP2F(x) __builtin_amdgcn_exp2f(x)
#else
#define EXP2F(x) __expf((x) * 0.69314718f)
#endif

#if __has_builtin(__builtin_amdgcn_rcpf)
#define RCPF(x) __builtin_amdgcn_rcpf(x)
#else
#define RCPF(x) (1.0f / (x))
#endif

// Analytic lookup-table inverse (fallback path): pixel index of axial (q,r)
// is col_base(q) + r. Verified by rounds 1-4 passing.
__device__ __forceinline__ int col_base(int q) {
    int a = q + 24;
    return (q <= 0) ? (a * 26 + ((a * (a - 1)) >> 1))
                    : (900 + 49 * q - ((q * (q - 1)) >> 1));
}

__device__ __forceinline__ bool in_hex(int q, int r) {
    return (unsigned)(q + 24) <= 48u && (unsigned)(r + 24) <= 48u &&
           (unsigned)(q + r + 24) <= 48u;
}

__global__ __launch_bounds__(NT) void hexsplat_kernel(
    const float* __restrict__ xs, const float* __restrict__ ys,
    const float* __restrict__ vs, unsigned int* __restrict__ acc,
    int n4, int slice_mask)
{
    __shared__ unsigned int hist[2 * NPIX];   // lane-parity split copies
    #pragma unroll 4
    for (int i = threadIdx.x; i < 2 * NPIX; i += NT) hist[i] = 0u;
    __syncthreads();

    const int pbase = (threadIdx.x & 1) ? NPIX : 0;
    const int tid = blockIdx.x * NT + threadIdx.x;
    const int stride = NB * NT;
    const float4* x4 = (const float4*)xs;
    const float4* y4 = (const float4*)ys;
    const float4* v4 = (const float4*)vs;

    for (int i = tid; i < n4; i += stride) {
        float4 xq = x4[i];
        float4 yq = y4[i];
        float4 vq = v4[i];
        #pragma unroll
        for (int k = 0; k < 4; ++k) {
            float px = (&xq.x)[k];
            float py = (&yq.x)[k];
            float pv = (&vq.x)[k];

            // cartesian -> fractional axial (hex_size == 1, rot == 0, offset == 0)
            float q = fmaf(-0.33333334f, py, 0.57735027f * px);
            float r = 0.66666669f * py;

            // cube round, matching jnp.round (half-to-even)
            float sn = -q - r;
            float qi = rintf(q), ri = rintf(r), si = rintf(sn);
            float dq = fabsf(qi - q), dr = fabsf(ri - r), ds = fabsf(si - sn);
            if (dq > dr && dq > ds)      qi = -ri - si;
            else if (dr > dq && dr > ds) ri = -qi - si;

            int qb = (int)qi;
            int rb = (int)ri;

            float dx = fmaf(-1.7320508f, fmaf(0.5f, ri, qi), px);
            float dy = fmaf(-1.5f, ri, py);

            // shared subexpressions: 3 distinct dyn, 5 distinct dxn
            float dm = dy - 1.5f,        dp = dy + 1.5f;
            float em = dx - 0.8660254f,  ep = dx + 0.8660254f;
            float eM = dx - 1.7320508f,  eP = dx + 1.7320508f;
            // pre-scaled |dyn| terms (K folded in); abs folds to input modifier
            float c0 = KHD * fabsf(dy), cm = KHD * fabsf(dm), cp = KHD * fabsf(dp);
            float h0 = 0.5f * c0,       hm = 0.5f * cm,       hp = 0.5f * cp;
            // u_n = K * hex-metric distance to neighbor n; w_n = exp2(-u_n^2)
            float u0 = fmaxf(c0, fmaf(KHX, fabsf(eP), h0));   // (-1, 0)
            float u1 = fmaxf(cm, fmaf(KHX, fabsf(ep), hm));   // (-1, 1)
            float u2 = fmaxf(cp, fmaf(KHX, fabsf(ep), hp));   // ( 0,-1)
            float u3 = fmaxf(c0, fmaf(KHX, fabsf(dx), h0));   // ( 0, 0)
            float u4 = fmaxf(cm, fmaf(KHX, fabsf(em), hm));   // ( 0, 1)
            float u5 = fmaxf(cp, fmaf(KHX, fabsf(em), hp));   // ( 1,-1)
            float u6 = fmaxf(c0, fmaf(KHX, fabsf(eM), h0));   // ( 1, 0)
            float w0 = EXP2F(-(u0 * u0));
            float w1 = EXP2F(-(u1 * u1));
            float w2 = EXP2F(-(u2 * u2));
            float w3 = EXP2F(-(u3 * u3));
            float w4 = EXP2F(-(u4 * u4));
            float w5 = EXP2F(-(u5 * u5));
            float w6 = EXP2F(-(u6 * u6));
            float wsum = ((w0 + w1) + (w2 + w3)) + ((w4 + w5) + w6);
            float vinv = (pv * FXSCALE) * RCPF(wsum);

            bool interior = ((unsigned)(qb + 23) <= 46u) &
                            ((unsigned)(rb + 23) <= 46u) &
                            ((unsigned)(qb + rb + 23) <= 46u);
            if (interior) {
                // closed form: col_base(q) = 900 + sgn(q) * (|q|(99-|q|) >> 1)
                int m  = qb < 0 ? -qb : qb;
                int t  = (m * (99 - m)) >> 1;
                int b1 = 900 + rb + pbase + (qb < 0 ? -t : t);
                // column-width deltas: col_base(q)-col_base(q-1) = (99-|2q-1|)>>1
                int t2 = qb + qb;
                int a0 = t2 - 1; a0 = a0 < 0 ? -a0 : a0;
                int a2 = t2 + 1; a2 = a2 < 0 ? -a2 : a2;
                int A0 = b1 - ((99 - a0) >> 1);   // col_base(qb-1)+rb+pbase
                int A2 = b1 + ((99 - a2) >> 1);   // col_base(qb+1)+rb+pbase
                atomicAdd(&hist[A0],     (unsigned int)(int)(w0 * vinv));
                atomicAdd(&hist[A0 + 1], (unsigned int)(int)(w1 * vinv));
                atomicAdd(&hist[b1 - 1], (unsigned int)(int)(w2 * vinv));
                atomicAdd(&hist[b1],     (unsigned int)(int)(w3 * vinv));
                atomicAdd(&hist[b1 + 1], (unsigned int)(int)(w4 * vinv));
                atomicAdd(&hist[A2 - 1], (unsigned int)(int)(w5 * vinv));
                atomicAdd(&hist[A2],     (unsigned int)(int)(w6 * vinv));
            } else {
                const int nq_[7] = {-1, -1, 0, 0, 0, 1, 1};
                const int nr_[7] = {0, 1, -1, 0, 1, -1, 0};
                float warr[7] = {w0, w1, w2, w3, w4, w5, w6};
                #pragma unroll
                for (int nn = 0; nn < 7; ++nn) {
                    int qn = qb + nq_[nn];
                    int rn = rb + nr_[nn];
                    if (in_hex(qn, rn)) {
                        atomicAdd(&hist[col_base(qn) + rn + pbase],
                                  (unsigned int)(int)(warr[nn] * vinv));
                    }
                }
            }
        }
    }

    __syncthreads();
    unsigned int* aslice = acc + (size_t)(blockIdx.x & slice_mask) * NPIX;
    for (int i = threadIdx.x; i < NPIX; i += NT) {
        atomicAdd(&aslice[i], hist[i] + hist[i + NPIX]);   // exact mod-2^32
    }
}

__global__ void finalize_kernel(const unsigned int* __restrict__ acc,
                                float* __restrict__ out, int nslices)
{
    int i = blockIdx.x * blockDim.x + threadIdx.x;
    if (i < NPIX) {
        unsigned int s = 0;
        for (int k = 0; k < nslices; ++k) s += acc[(size_t)k * NPIX + i];
        out[i] = (float)(int)s * FXINV;
    }
}

extern "C" void kernel_launch(void* const* d_in, const int* in_sizes, int n_in,
                              void* d_out, int out_size, void* d_ws, size_t ws_size,
                              hipStream_t stream) {
    const float* x = (const float*)d_in[0];
    const float* y = (const float*)d_in[1];
    const float* v = (const float*)d_in[2];
    float* out = (float*)d_out;
    unsigned int* acc = (unsigned int*)d_ws;
    int n = in_sizes[0];
    int n4 = n / 4;

    // as many power-of-two accumulator slices as the workspace allows (<=32)
    int nslices = 1;
    while (nslices < MAXSLICES &&
           (size_t)(nslices * 2) * NPIX * sizeof(unsigned int) <= ws_size)
        nslices *= 2;

    hipMemsetAsync(acc, 0, (size_t)nslices * NPIX * sizeof(unsigned int), stream);
    hexsplat_kernel<<<NB, NT, 0, stream>>>(x, y, v, acc, n4, nslices - 1);
    finalize_kernel<<<(NPIX + 255) / 256, 256, 0, stream>>>(acc, out, nslices);
}